// Round 7
// baseline (49.517 us; speedup 1.0000x reference)
//
#include <hip/hip_runtime.h>

#define NT   256  // 4 waves/block; waves fully independent (zero __syncthreads)
#define WSZ  64
#define SPW  32   // samples per wave (2 lanes per sample)
#define NJ   22

// per-step schedules: lane h=0 runs cJ0 chain-set, h=1 runs cJ1.
// src: 0 = previous g, 1 = g0 (root), 2 = g9 (broadcast from partner lane)
__constant__ __device__ const int dummy_unused = 0; // (no runtime table; all constexpr)

constexpr int cJ0[11] = {3,6,9, 2,5,8,11, 13,16,18,20};
constexpr int cS0[11] = {1,0,0, 1,0,0,0,  2, 0, 0, 0};
constexpr int cJ1[11] = {1,4,7,10, 12,15, 14,17,19,21, 12};
constexpr int cS1[11] = {1,0,0,0,  2, 0,  2, 0, 0, 0,  2};  // t10 = benign recompute of j12

__device__ __forceinline__ void rodrigues(float ax, float ay, float az, float* R) {
    float sq   = ax*ax + ay*ay + az*az + 1e-12f;
    float rinv = rsqrtf(sq);
    float ang  = sq * rinv;          // sqrt(sq)
    float s, c;
    __sincosf(ang, &s, &c);
    float x = ax*rinv, y = ay*rinv, z = az*rinv;
    float t = 1.0f - c;
    R[0] = t*x*x + c;   R[1] = t*x*y - s*z; R[2] = t*x*z + s*y;
    R[3] = t*x*y + s*z; R[4] = t*y*y + c;   R[5] = t*y*z - s*x;
    R[6] = t*x*z - s*y; R[7] = t*y*z + s*x; R[8] = t*z*z + c;
}

// Row layout (12 floats): [d0..d9, LT, 0]. local = LT + sum_k bt[k]*d[k]. j may be runtime.
__device__ __forceinline__ void local_pos_rt(int j, const float* bt,
                                             const float4* LD4, float* lt) {
    #pragma unroll
    for (int c = 0; c < 3; ++c) {
        const float4 a0 = LD4[(j*3 + c)*3 + 0];
        const float4 a1 = LD4[(j*3 + c)*3 + 1];
        const float4 a2 = LD4[(j*3 + c)*3 + 2];
        float v = a2.z;                                  // LT in pad slot
        v = fmaf(bt[0], a0.x, v); v = fmaf(bt[1], a0.y, v);
        v = fmaf(bt[2], a0.z, v); v = fmaf(bt[3], a0.w, v);
        v = fmaf(bt[4], a1.x, v); v = fmaf(bt[5], a1.y, v);
        v = fmaf(bt[6], a1.z, v); v = fmaf(bt[7], a1.w, v);
        v = fmaf(bt[8], a2.x, v); v = fmaf(bt[9], a2.y, v);
        lt[c] = v;
    }
}

template<int S>
__device__ __forceinline__ const float* psel(const float* g, const float* g0, const float* g9s) {
    if constexpr (S == 0) return g;
    else if constexpr (S == 1) return g0;
    else return g9s;
}

// one lane-parallel FK step; g[12] = running transform (r0..8, t9..11)
template<int T>
__device__ __forceinline__ void step2(float* g, const float* g0, const float* g9s,
                                      int h, const float* aa, const float* bt,
                                      const float4* LD4, float* s_o /* samp*66 base */) {
    constexpr int J0 = cJ0[T], J1 = cJ1[T], S0 = cS0[T], S1 = cS1[T];
    // parent select (uniform code; per-lane data)
    float gp[12];
    if constexpr (S0 == S1) {
        const float* a = psel<S0>(g, g0, g9s);
        #pragma unroll
        for (int i = 0; i < 12; ++i) gp[i] = a[i];
    } else {
        const float* a = psel<S0>(g, g0, g9s);
        const float* b = psel<S1>(g, g0, g9s);
        #pragma unroll
        for (int i = 0; i < 12; ++i) gp[i] = h ? b[i] : a[i];
    }
    const int j = h ? J1 : J0;
    float R[9];
    rodrigues(aa[T*3 + 0], aa[T*3 + 1], aa[T*3 + 2], R);
    float lt[3];
    local_pos_rt(j, bt, LD4, lt);
    float gn[12];
    #pragma unroll
    for (int r = 0; r < 3; ++r) {
        #pragma unroll
        for (int c = 0; c < 3; ++c)
            gn[r*3+c] = fmaf(gp[r*3+0], R[c],
                        fmaf(gp[r*3+1], R[3+c],
                             gp[r*3+2] * R[6+c]));
        gn[9+r] = fmaf(gp[r*3+0], lt[0],
                  fmaf(gp[r*3+1], lt[1],
                  fmaf(gp[r*3+2], lt[2], gp[9+r])));
    }
    s_o[j*3+0] = gn[9]; s_o[j*3+1] = gn[10]; s_o[j*3+2] = gn[11];
    #pragma unroll
    for (int i = 0; i < 12; ++i) g[i] = gn[i];
}

__global__ __launch_bounds__(NT, 4) void fk_joints_kernel(
    const float* __restrict__ body_pose,     // (S,63)
    const float* __restrict__ betas,         // (S,10)
    const float* __restrict__ global_orient, // (S,3)
    const float* __restrict__ transl,        // (S,3)
    const float* __restrict__ J_template,    // (22,3)
    const float* __restrict__ J_shapedirs,   // (22,3,10)
    float* __restrict__ out)                 // (S,22,3)
{
    // Wave-private regions of 32 samples x 66 floats: pose (32x63) staged at the
    // head; FK outputs overlay the region AFTER all pose floats are in registers.
    __shared__ float  s_buf[4 * SPW * 66];   // 4 waves * 2112 floats = 33792 B
    __shared__ float4 s_LD4[NJ*3*3];         // 66 rows x 12 floats: [dirs(10), LT, 0]

    const int  tid  = threadIdx.x;
    const int  lane = tid & (WSZ-1);
    const int  wid  = tid >> 6;
    const int  samp = lane >> 1;             // 0..31 local sample
    const int  h    = lane & 1;              // half: which chain-set this lane runs
    const long long sw = (long long)blockIdx.x * (4*SPW) + (long long)wid * SPW;
    const long long s  = sw + samp;          // this lane's sample (pairs share s)

    // ---- direct per-lane loads of small inputs (pair-duplicated; coalescer merges) ----
    const float gox = global_orient[s*3 + 0];
    const float goy = global_orient[s*3 + 1];
    const float goz = global_orient[s*3 + 2];
    const float trx = transl[s*3 + 0];
    const float try_ = transl[s*3 + 1];
    const float trz = transl[s*3 + 2];
    float bt[10];
    {
        const float2* b2 = reinterpret_cast<const float2*>(betas + s*10);
        #pragma unroll
        for (int k = 0; k < 5; ++k) {
            float2 v = b2[k];
            bt[2*k+0] = v.x; bt[2*k+1] = v.y;
        }
    }

    // ---- stage OWN wave's 32-sample pose chunk (coalesced float4) ----
    float* myb = s_buf + wid * (SPW*66);
    {
        const float4* src = reinterpret_cast<const float4*>(body_pose + sw*63);
        float4* dst = reinterpret_cast<float4*>(myb);
        #pragma unroll
        for (int i = lane; i < SPW*63/4; i += WSZ) dst[i] = src[i];   // 504 f4
    }

    // ---- tables: EACH wave writes identical values (benign duplicate) ----
    const int P[NJ] = {0,0,0,0,1,2,3,4,5,6,7,8,9,9,9,12,13,14,16,17,18,19};
    float* s_LD = reinterpret_cast<float*>(s_LD4);
    for (int i = lane; i < NJ*3; i += WSZ) {
        int j = i/3, c = i - j*3;
        float v = J_template[i];
        if (j) v -= J_template[P[j]*3 + c];
        s_LD[i*12 + 10] = v;       // LT in pad slot
        s_LD[i*12 + 11] = 0.0f;
    }
    for (int i = lane; i < NJ*30; i += WSZ) {
        int jc = i/10, k = i - jc*10;
        int j = jc/3,  c = jc - j*3;
        float v = J_shapedirs[i];
        if (j) v -= J_shapedirs[(P[j]*3 + c)*10 + k];
        s_LD[jc*12 + k] = v;
    }
    __builtin_amdgcn_wave_barrier();   // fence: staging/table writes before reads

    // ---- pre-read THIS lane's 11 steps x 3 aa floats into registers ----
    float aa[33];
    {
        const float* mypose = myb + samp*63;
        #pragma unroll
        for (int t = 0; t < 11; ++t) {
            const int off = (h ? (cJ1[t]-1) : (cJ0[t]-1)) * 3;   // cndmask of 2 consts
            aa[t*3+0] = mypose[off+0];
            aa[t*3+1] = mypose[off+1];
            aa[t*3+2] = mypose[off+2];
        }
    }

    // ---- root transform g0 (both lanes of a pair compute identically) ----
    float g0[12];
    rodrigues(gox, goy, goz, g0);
    {
        float lt0[3];
        local_pos_rt(0, bt, s_LD4, lt0);
        g0[9]  = lt0[0] + trx;
        g0[10] = lt0[1] + try_;
        g0[11] = lt0[2] + trz;
    }
    __builtin_amdgcn_wave_barrier();   // fence: ALL pose reads done before output overlay

    float* s_o = myb + samp*66;
    s_o[0] = g0[9]; s_o[1] = g0[10]; s_o[2] = g0[11];   // root (dup write, same value)

    // ---- 11 lane-parallel steps; g9 broadcast to partner after t=2 ----
    float g[12];
    float g9s[12];
    #pragma unroll
    for (int i = 0; i < 12; ++i) g9s[i] = 0.0f;   // not used before t>=4 broadcast

    step2<0>(g, g0, g9s, h, aa, bt, s_LD4, s_o);
    step2<1>(g, g0, g9s, h, aa, bt, s_LD4, s_o);
    step2<2>(g, g0, g9s, h, aa, bt, s_LD4, s_o);
    // after t=2: lane h=0 holds g9; broadcast to both lanes of the pair
    {
        const int pairlane = lane & ~1;
        #pragma unroll
        for (int i = 0; i < 12; ++i) g9s[i] = __shfl(g[i], pairlane, WSZ);
    }
    step2<3>(g, g0, g9s, h, aa, bt, s_LD4, s_o);
    step2<4>(g, g0, g9s, h, aa, bt, s_LD4, s_o);
    step2<5>(g, g0, g9s, h, aa, bt, s_LD4, s_o);
    step2<6>(g, g0, g9s, h, aa, bt, s_LD4, s_o);
    step2<7>(g, g0, g9s, h, aa, bt, s_LD4, s_o);
    step2<8>(g, g0, g9s, h, aa, bt, s_LD4, s_o);
    step2<9>(g, g0, g9s, h, aa, bt, s_LD4, s_o);
    step2<10>(g, g0, g9s, h, aa, bt, s_LD4, s_o);

    __builtin_amdgcn_wave_barrier();   // fence: FK writes before gather reads

    // ---- coalesced float4 copy of OWN wave's output region (2112 floats) ----
    {
        const float4* src = reinterpret_cast<const float4*>(myb);
        float4* dst = reinterpret_cast<float4*>(out + sw * (NJ*3));
        for (int i = lane; i < SPW*66/4; i += WSZ) dst[i] = src[i];   // 528 f4
    }
}

extern "C" void kernel_launch(void* const* d_in, const int* in_sizes, int n_in,
                              void* d_out, int out_size, void* d_ws, size_t ws_size,
                              hipStream_t stream) {
    const float* body_pose     = (const float*)d_in[0];
    const float* betas         = (const float*)d_in[1];
    const float* global_orient = (const float*)d_in[2];
    const float* transl        = (const float*)d_in[3];
    const float* J_template    = (const float*)d_in[4];
    const float* J_shapedirs   = (const float*)d_in[5];
    float* out = (float*)d_out;

    const int S = in_sizes[0] / 63;          // B*L = 131072
    const int blocks = S / (4*SPW);          // 128 samples per 256-thread block

    hipLaunchKernelGGL(fk_joints_kernel, dim3(blocks), dim3(NT), 0, stream,
                       body_pose, betas, global_orient, transl,
                       J_template, J_shapedirs, out);
}

// Round 8
// 37.382 us; speedup vs baseline: 1.3246x; 1.3246x over previous
//
#include <hip/hip_runtime.h>

#define NT  128  // 2 waves/block; waves fully independent (zero __syncthreads)
#define WSZ 64
#define NJ  22

typedef const __attribute__((address_space(1))) void* gas1_t;
typedef __attribute__((address_space(3))) void* las3_t;

// async global->LDS DMA, 16B/lane: LDS dest = uniform base + lane*16, global src per-lane
__device__ __forceinline__ void gload_lds16(const void* g, void* l) {
    __builtin_amdgcn_global_load_lds((gas1_t)g, (las3_t)l, 16, 0, 0);
}

struct X9 { float r[9]; float t[3]; };

__device__ __forceinline__ void rodrigues(float ax, float ay, float az, float* R) {
    float sq   = ax*ax + ay*ay + az*az + 1e-12f;
    float rinv = rsqrtf(sq);
    float ang  = sq * rinv;          // sqrt(sq)
    float s, c;
    __sincosf(ang, &s, &c);
    float x = ax*rinv, y = ay*rinv, z = az*rinv;
    float t = 1.0f - c;
    R[0] = t*x*x + c;   R[1] = t*x*y - s*z; R[2] = t*x*z + s*y;
    R[3] = t*x*y + s*z; R[4] = t*y*y + c;   R[5] = t*y*z - s*x;
    R[6] = t*x*z - s*y; R[7] = t*y*z + s*x; R[8] = t*z*z + c;
}

// Row layout (12 floats): [d0..d9, LT, 0].  local = LT + sum_k bt[k]*d[k]
__device__ __forceinline__ void local_pos(int j, const float* bt,
                                          const float4* LD4, float* lt) {
    #pragma unroll
    for (int c = 0; c < 3; ++c) {
        const float4 a0 = LD4[(j*3 + c)*3 + 0];
        const float4 a1 = LD4[(j*3 + c)*3 + 1];
        const float4 a2 = LD4[(j*3 + c)*3 + 2];
        float v = a2.z;                                  // LT folded into pad slot
        v = fmaf(bt[0], a0.x, v); v = fmaf(bt[1], a0.y, v);
        v = fmaf(bt[2], a0.z, v); v = fmaf(bt[3], a0.w, v);
        v = fmaf(bt[4], a1.x, v); v = fmaf(bt[5], a1.y, v);
        v = fmaf(bt[6], a1.z, v); v = fmaf(bt[7], a1.w, v);
        v = fmaf(bt[8], a2.x, v); v = fmaf(bt[9], a2.y, v);
        lt[c] = v;
    }
}

template<int J>
__device__ __forceinline__ X9 step(const X9& gp, const float* aa, const float* bt,
                                   const float4* LD4, float* s_o) {
    float R[9];
    rodrigues(aa[(J-1)*3 + 0], aa[(J-1)*3 + 1], aa[(J-1)*3 + 2], R);
    float lt[3];
    local_pos(J, bt, LD4, lt);
    X9 g;
    #pragma unroll
    for (int r = 0; r < 3; ++r) {
        #pragma unroll
        for (int c = 0; c < 3; ++c)
            g.r[r*3+c] = fmaf(gp.r[r*3+0], R[c],
                         fmaf(gp.r[r*3+1], R[3+c],
                              gp.r[r*3+2] * R[6+c]));
        g.t[r] = fmaf(gp.r[r*3+0], lt[0],
                 fmaf(gp.r[r*3+1], lt[1],
                 fmaf(gp.r[r*3+2], lt[2], gp.t[r])));
    }
    s_o[J*3+0] = g.t[0]; s_o[J*3+1] = g.t[1]; s_o[J*3+2] = g.t[2];
    return g;
}

__global__ __launch_bounds__(NT) void fk_joints_kernel(
    const float* __restrict__ body_pose,     // (S,63)
    const float* __restrict__ betas,         // (S,10)
    const float* __restrict__ global_orient, // (S,3)
    const float* __restrict__ transl,        // (S,3)
    const float* __restrict__ J_template,    // (22,3)
    const float* __restrict__ J_shapedirs,   // (22,3,10)
    float* __restrict__ out)                 // (S,22,3)
{
    // Wave-private regions (64 samples x 66 floats): pose staged packed (64x63) at
    // region head via global_load_lds DMA; FK outputs overlay the region (64x66)
    // only after all pose floats are register-resident (in-order DS pipe + fences).
    __shared__ float  s_buf[NT*66];          // 33792 B
    __shared__ float4 s_LD4[NJ*3*3];         // 66 rows x 12 floats: [dirs(10), LT, 0]

    const int  tid  = threadIdx.x;
    const int  lane = tid & (WSZ-1);
    const int  wid  = tid >> 6;
    const long long sw = (long long)blockIdx.x * NT + (long long)wid * WSZ;
    const long long s  = sw + lane;

    float* myb = s_buf + wid * (WSZ*66);

    // ---- 1) issue pose DMA first (longest latency, no VGPR round-trip) ----
    {
        const float4* src = reinterpret_cast<const float4*>(body_pose + sw*63);
        float4* dst = reinterpret_cast<float4*>(myb);
        #pragma unroll
        for (int k = 0; k < 15; ++k)
            gload_lds16(src + (k*WSZ + lane), dst + k*WSZ);   // 960 of 1008 f4
    }

    // ---- 2) per-lane small-input loads (fill under the DMA) ----
    const float gox = global_orient[s*3 + 0];
    const float goy = global_orient[s*3 + 1];
    const float goz = global_orient[s*3 + 2];
    const float trx = transl[s*3 + 0];
    const float try_ = transl[s*3 + 1];
    const float trz = transl[s*3 + 2];
    float bt[10];
    {
        const float2* b2 = reinterpret_cast<const float2*>(betas + s*10);
        #pragma unroll
        for (int k = 0; k < 5; ++k) {
            float2 v = b2[k];
            bt[2*k+0] = v.x; bt[2*k+1] = v.y;
        }
    }

    // ---- 3) staging tail (48 f4) via normal path ----
    {
        const float4* src = reinterpret_cast<const float4*>(body_pose + sw*63);
        float4* dst = reinterpret_cast<float4*>(myb);
        if (lane < 48) dst[960 + lane] = src[960 + lane];
    }

    // ---- 4) tables: EACH wave writes identical values (benign duplicate) ----
    const int P[NJ] = {0,0,0,0,1,2,3,4,5,6,7,8,9,9,9,12,13,14,16,17,18,19};
    float* s_LD = reinterpret_cast<float*>(s_LD4);
    for (int i = lane; i < NJ*3; i += WSZ) {
        int j = i/3, c = i - j*3;
        float v = J_template[i];
        if (j) v -= J_template[P[j]*3 + c];
        s_LD[i*12 + 10] = v;       // LT in pad slot
        s_LD[i*12 + 11] = 0.0f;
    }
    for (int i = lane; i < NJ*30; i += WSZ) {
        int jc = i/10, k = i - jc*10;
        int j = jc/3,  c = jc - j*3;
        float v = J_shapedirs[i];
        if (j) v -= J_shapedirs[(P[j]*3 + c)*10 + k];
        s_LD[jc*12 + k] = v;
    }

    // ---- 5) drain the DMA (compiler can't connect global_load_lds -> ds_read) ----
    asm volatile("s_waitcnt vmcnt(0)" ::: "memory");
    __builtin_amdgcn_wave_barrier();   // fence: staging/table writes before reads

    // ---- 6) transpose read: own 63 pose floats -> registers (stride 63, conflict-free) ----
    float aa[63];
    #pragma unroll
    for (int k = 0; k < 63; ++k) aa[k] = myb[lane*63 + k];
    __builtin_amdgcn_wave_barrier();   // fence: ALL pose reads before output overlay

    // ---- 7) FK fully in registers; joint positions -> myb[lane*66 + ...] ----
    float* s_o = myb + lane*66;

    X9 g0;
    rodrigues(gox, goy, goz, g0.r);
    {
        float lt0[3];
        local_pos(0, bt, s_LD4, lt0);
        g0.t[0] = lt0[0] + trx;
        g0.t[1] = lt0[1] + try_;
        g0.t[2] = lt0[2] + trz;
        s_o[0] = g0.t[0]; s_o[1] = g0.t[1]; s_o[2] = g0.t[2];
    }

    X9 g;
    // chain A: 0 -> 1 -> 4 -> 7 -> 10
    g = step<1 >(g0, aa, bt, s_LD4, s_o);
    g = step<4 >(g,  aa, bt, s_LD4, s_o);
    g = step<7 >(g,  aa, bt, s_LD4, s_o);
    g = step<10>(g,  aa, bt, s_LD4, s_o);
    // chain B: 0 -> 2 -> 5 -> 8 -> 11
    g = step<2 >(g0, aa, bt, s_LD4, s_o);
    g = step<5 >(g,  aa, bt, s_LD4, s_o);
    g = step<8 >(g,  aa, bt, s_LD4, s_o);
    g = step<11>(g,  aa, bt, s_LD4, s_o);
    // chain C: 0 -> 3 -> 6 -> 9
    g = step<3 >(g0, aa, bt, s_LD4, s_o);
    g = step<6 >(g,  aa, bt, s_LD4, s_o);
    X9 g9 = step<9>(g, aa, bt, s_LD4, s_o);
    // chain D: 9 -> 12 -> 15
    g = step<12>(g9, aa, bt, s_LD4, s_o);
    g = step<15>(g,  aa, bt, s_LD4, s_o);
    // chain E: 9 -> 13 -> 16 -> 18 -> 20
    g = step<13>(g9, aa, bt, s_LD4, s_o);
    g = step<16>(g,  aa, bt, s_LD4, s_o);
    g = step<18>(g,  aa, bt, s_LD4, s_o);
    g = step<20>(g,  aa, bt, s_LD4, s_o);
    // chain F: 9 -> 14 -> 17 -> 19 -> 21
    g = step<14>(g9, aa, bt, s_LD4, s_o);
    g = step<17>(g,  aa, bt, s_LD4, s_o);
    g = step<19>(g,  aa, bt, s_LD4, s_o);
    g = step<21>(g,  aa, bt, s_LD4, s_o);

    __builtin_amdgcn_wave_barrier();   // fence: FK writes before gather reads

    // ---- 8) coalesced float4 copy of OWN wave's output region ----
    {
        const float4* src = reinterpret_cast<const float4*>(myb);
        float4* dst = reinterpret_cast<float4*>(out + sw * (NJ*3));
        #pragma unroll
        for (int i = lane; i < WSZ*66/4; i += WSZ) dst[i] = src[i];   // 1056 f4
    }
}

extern "C" void kernel_launch(void* const* d_in, const int* in_sizes, int n_in,
                              void* d_out, int out_size, void* d_ws, size_t ws_size,
                              hipStream_t stream) {
    const float* body_pose     = (const float*)d_in[0];
    const float* betas         = (const float*)d_in[1];
    const float* global_orient = (const float*)d_in[2];
    const float* transl        = (const float*)d_in[3];
    const float* J_template    = (const float*)d_in[4];
    const float* J_shapedirs   = (const float*)d_in[5];
    float* out = (float*)d_out;

    const int S = in_sizes[0] / 63;        // B*L = 131072 (divisible by NT)
    const int blocks = S / NT;

    hipLaunchKernelGGL(fk_joints_kernel, dim3(blocks), dim3(NT), 0, stream,
                       body_pose, betas, global_orient, transl,
                       J_template, J_shapedirs, out);
}